// Round 5
// baseline (1072.333 us; speedup 1.0000x reference)
//
#include <hip/hip_runtime.h>

typedef _Float16 f16;
typedef _Float16 f16x8 __attribute__((ext_vector_type(8)));
typedef _Float16 f16x4 __attribute__((ext_vector_type(4)));
typedef float    f32x4 __attribute__((ext_vector_type(4)));
typedef unsigned long long u64;

// Problem constants: B=32, T=128, L=512, D=256, M=4, VOCAB=32000, HOPS=3
// DTYPE: ALL float inputs/outputs are fp32.

__device__ __forceinline__ float frcp(float x){
  float r; asm("v_rcp_f32 %0, %1" : "=v"(r) : "v"(x)); return r;
}
__device__ __forceinline__ float fsig(float x){ return frcp(1.0f + __expf(-x)); }
__device__ __forceinline__ float ftanh(float x){ return 2.0f*frcp(1.0f + __expf(-2.0f*x)) - 1.0f; }

// ---------------------------------------------------------------------------
__global__ void k_zero(float* out){
  int i = blockIdx.x*256 + threadIdx.x;
  if (i < 24576) out[i] = 0.f;
}

// ---------------------------------------------------------------------------
// K0: fp32 -> f16 weights + per-launch epoch increment (for k_gru_duo flags).
__global__ void k_cvtall(const float* __restrict__ s0, const float* __restrict__ s1,
                         const float* __restrict__ s2, const float* __restrict__ s3,
                         const float* __restrict__ s4,
                         f16* __restrict__ d0, f16* __restrict__ d1,
                         f16* __restrict__ d2, f16* __restrict__ d3,
                         f16* __restrict__ d4, unsigned* epoch){
  int i = blockIdx.x*256 + threadIdx.x;          // grid covers 196608
  if (epoch && i == 0) atomicAdd(epoch, 1u);
  d0[i] = (f16)s0[i];                            // Wih_f  [768*256]
  d1[i] = (f16)s1[i];                            // Wih_b
  d2[i] = (f16)s2[i];                            // Whh_f
  d3[i] = (f16)s3[i];                            // Whh_b
  if (i < 131072) d4[i] = (f16)s4[i];            // W_w    [256*512]
}

// ---------------------------------------------------------------------------
// K1: embed-bag: emb[b*128+t][d] = sum_m emb_ctx[conv[b,t,m]][d]  (f16 out)
__global__ void k_embbag(const int* __restrict__ conv, const float* __restrict__ tbl,
                         f16* __restrict__ emb){
  int bt = blockIdx.x, d = threadIdx.x;
  const int* ix = conv + (size_t)bt*4;
  float s = 0.f;
#pragma unroll
  for (int m = 0; m < 4; ++m) s += tbl[(size_t)ix[m]*256 + d];
  emb[(size_t)bt*256 + d] = (f16)s;
}

// ---------------------------------------------------------------------------
// K2: gx[m=t*32+b][j] = emb_row . Wih[j] + bih[j] + (j<512 ? bhh[j] : 0)
__global__ __launch_bounds__(256) void k_gx(const f16* __restrict__ emb,
                                            const f16* __restrict__ W16,
                                            const float* __restrict__ bih,
                                            const float* __restrict__ bhh,
                                            f16* __restrict__ gx, int rev){
  int lane = threadIdx.x & 63, wv = threadIdx.x >> 6;
  int l16 = lane & 15, l4 = lane >> 4;
  int mrow = blockIdx.x*64 + wv*16;
  int m = mrow + l16;
  int t = m >> 5, b = m & 31;
  int tsrc = rev ? (127 - t) : t;
  const f16* arow = emb + (size_t)(b*128 + tsrc)*256;
  f16x8 af[8];
#pragma unroll
  for (int kt = 0; kt < 8; ++kt) af[kt] = *(const f16x8*)(arow + kt*32 + l4*8);

  for (int nt = 0; nt < 48; ++nt){
    int n = nt*16 + l16;
    const f16* brow = W16 + (size_t)n*256;   // B[k][n] = Wih[n][k]
    f32x4 acc = {0.f,0.f,0.f,0.f};
#pragma unroll
    for (int kt = 0; kt < 8; ++kt){
      f16x8 bf = *(const f16x8*)(brow + kt*32 + l4*8);
      acc = __builtin_amdgcn_mfma_f32_16x16x32_f16(af[kt], bf, acc, 0, 0, 0);
    }
    float bias = bih[n] + (n < 512 ? bhh[n] : 0.f);
#pragma unroll
    for (int r = 0; r < 4; ++r){
      int m2 = mrow + l4*4 + r;
      gx[(size_t)m2*768 + n] = (f16)(acc[r] + bias);
    }
  }
}

// ---------------------------------------------------------------------------
// K3a: GRU solo (round-3 proven 344-us kernel). 4 blocks, 512 threads.
// Used only when ws lacks the 132KB exchange extension.
__global__ __launch_bounds__(512, 1) void k_gru_solo(const f16* __restrict__ gx_f,
                                                     const f16* __restrict__ gx_b,
                                                     const f16* __restrict__ whhf16,
                                                     const f16* __restrict__ whhb16,
                                                     const float* __restrict__ bhh_f,
                                                     const float* __restrict__ bhh_b,
                                                     f16* __restrict__ Abuf){
  int dir = blockIdx.x >> 1, grp = blockIdx.x & 1, b0 = grp*16;
  const f16*   gx  = dir ? gx_b   : gx_f;
  const f16*   Whh = dir ? whhb16 : whhf16;
  const float* bhh = dir ? bhh_b  : bhh_f;

  int tid = threadIdx.x, lane = tid & 63, wv = tid >> 6;
  int l16 = lane & 15, l4 = lane >> 4;

  __shared__ __align__(16) f16   a16[2][16][264];
  __shared__ __align__(16) float bhnL[256];
  for (int i = tid; i < (16*264*2)/4; i += 512) ((unsigned*)&a16[0][0][0])[i] = 0u;
  if (tid < 256) bhnL[tid] = bhh[512 + tid];

  f16x8 aW[2][3][8];
#pragma unroll
  for (int q = 0; q < 2; ++q){
    int Q = 2*wv + q;
#pragma unroll
    for (int g = 0; g < 3; ++g){
      const f16* wrow = Whh + (size_t)(g*256 + Q*16 + l16)*256;
#pragma unroll
      for (int kt = 0; kt < 8; ++kt) aW[q][g][kt] = *(const f16x8*)(wrow + kt*32 + l4*8);
    }
  }

  const f16* gp = gx + (size_t)(b0 + l16)*768;
  f16* ap  = Abuf + (size_t)(b0 + l16)*128*512 + dir*256 + (size_t)(dir ? 127 : 0)*512;
  int  astep = dir ? -512 : 512;
  f16* app = ap;

  const int d00 = (2*wv    )*16 + l4*4;
  const int d01 = (2*wv + 1)*16 + l4*4;

  f16x4 pend[2];
  pend[0] = (f16x4){(f16)0.f,(f16)0.f,(f16)0.f,(f16)0.f};
  pend[1] = (f16x4){(f16)0.f,(f16)0.f,(f16)0.f,(f16)0.f};

  __syncthreads();

#pragma unroll 1
  for (int t = 0; t < 128; ++t){
    if (t){
      *(f16x4*)(app + d00) = pend[0];
      *(f16x4*)(app + d01) = pend[1];
    }
    f16x4 xg[2][3];
#pragma unroll
    for (int q = 0; q < 2; ++q)
#pragma unroll
      for (int g = 0; g < 3; ++g)
        xg[q][g] = *(const f16x4*)(gp + g*256 + (2*wv+q)*16 + l4*4);

    const f16* rb = &a16[t & 1][l16][l4*8];

    f32x4 accr[2], accz[2];
#pragma unroll
    for (int q = 0; q < 2; ++q){ accr[q] = (f32x4){0.f,0.f,0.f,0.f};
                                 accz[q] = (f32x4){0.f,0.f,0.f,0.f}; }
#pragma unroll
    for (int kt = 0; kt < 8; ++kt){
      f16x8 bf = *(const f16x8*)(rb + kt*32);
#pragma unroll
      for (int q = 0; q < 2; ++q){
        accr[q] = __builtin_amdgcn_mfma_f32_16x16x32_f16(aW[q][0][kt], bf, accr[q], 0, 0, 0);
        accz[q] = __builtin_amdgcn_mfma_f32_16x16x32_f16(aW[q][1][kt], bf, accz[q], 0, 0, 0);
      }
    }
    f32x4 accn[2];
#pragma unroll
    for (int q = 0; q < 2; ++q) accn[q] = (f32x4){0.f,0.f,0.f,0.f};
#pragma unroll
    for (int kt = 0; kt < 8; ++kt){
      f16x8 bf = *(const f16x8*)(rb + kt*32);
#pragma unroll
      for (int q = 0; q < 2; ++q)
        accn[q] = __builtin_amdgcn_mfma_f32_16x16x32_f16(aW[q][2][kt], bf, accn[q], 0, 0, 0);
    }
    float rr[2][4], zz[2][4];
#pragma unroll
    for (int q = 0; q < 2; ++q)
#pragma unroll
      for (int r = 0; r < 4; ++r){
        rr[q][r] = fsig((float)xg[q][0][r] + accr[q][r]);
        zz[q][r] = fsig((float)xg[q][1][r] + accz[q][r]);
      }
    int nxt = (t & 1) ^ 1;
#pragma unroll
    for (int q = 0; q < 2; ++q){
      int d0 = (2*wv+q)*16 + l4*4;
      float4 bh4 = *(const float4*)(&bhnL[d0]);
      f16x4 hold = pend[q];
      f16x4 o4;
#pragma unroll
      for (int r = 0; r < 4; ++r){
        float bh = (r==0)?bh4.x:(r==1)?bh4.y:(r==2)?bh4.z:bh4.w;
        float nn = ftanh((float)xg[q][2][r] + rr[q][r]*(accn[q][r] + bh));
        float h2 = nn + zz[q][r]*((float)hold[r] - nn);
        o4[r] = (f16)h2;
      }
      *(f16x4*)(&a16[nxt][l16][d0]) = o4;
      pend[q] = o4;
    }
    app = ap; ap += astep;
    gp += 24576;
    __syncthreads();
  }
  *(f16x4*)(app + d00) = pend[0];
  *(f16x4*)(app + d01) = pend[1];
}

// ---------------------------------------------------------------------------
// K3b: GRU duo v6 — gate-split across block pairs. 8 blocks = (dir,grp,half),
// 512 threads (8 waves, 1 Q-tile/wave). Round-4 post-mortem: gfx950 unified
// VGPR/AGPR budget means weight residency REQUIRES <=2 waves/SIMD (256 regs);
// per-SIMD work is then fixed, so the only lever left is more CUs. Each half-
// block computes 128 of 256 h-cols (all 3 gates; per-SIMD MFMA 96->48) and
// exchanges its 4KB h-slice per step via LLC (agent-scope relaxed atomics,
// no L2 flushes) + release/acquire flag versioned by a per-launch epoch
// (replay-safe; deterministic hx makes stale-pass idempotent).
__global__ __launch_bounds__(512, 1) void k_gru_duo(const f16* __restrict__ gx_f,
                                                    const f16* __restrict__ gx_b,
                                                    const f16* __restrict__ whhf16,
                                                    const f16* __restrict__ whhb16,
                                                    const float* __restrict__ bhh_f,
                                                    const float* __restrict__ bhh_b,
                                                    f16* __restrict__ Abuf,
                                                    char* __restrict__ ext){
  int bid = blockIdx.x;
  int dir = bid >> 2, grp = (bid >> 1) & 1, half = bid & 1;
  int b0 = grp*16;
  const f16*   gx  = dir ? gx_b   : gx_f;
  const f16*   Whh = dir ? whhb16 : whhf16;
  const float* bhh = dir ? bhh_b  : bhh_f;

  int tid = threadIdx.x, lane = tid & 63, wv = tid >> 6;   // 8 waves
  int l16 = lane & 15, l4 = lane >> 4;

  __shared__ __align__(16) f16   a16[2][16][264];
  __shared__ __align__(16) float bhnL[256];
  for (int i = tid; i < (16*264*2)/4; i += 512) ((unsigned*)&a16[0][0][0])[i] = 0u;
  if (tid < 256) bhnL[tid] = bhh[512 + tid];

  // exchange region: hx slots [pairhalf][parity] of 4096B, then flags, epoch
  int pair = dir*2 + grp;
  char*     hx_mine    = ext + (size_t)((pair*2 + half      )*2)*4096;
  char*     hx_partner = ext + (size_t)((pair*2 + (half^1))*2)*4096;
  unsigned* flags_mine    = (unsigned*)(ext + 131072) + (pair*2 + half      )*128;
  unsigned* flags_partner = (unsigned*)(ext + 131072) + (pair*2 + (half^1))*128;
  unsigned epoch = __hip_atomic_load((unsigned*)(ext + 135168),
                                     __ATOMIC_RELAXED, __HIP_MEMORY_SCOPE_AGENT);

  const int Qg = half*8 + wv;          // global Q-tile 0..15
  const int d0 = Qg*16 + l4*4;         // global col 0..255 (own half)
  f16x8 aW[3][8];
#pragma unroll
  for (int g = 0; g < 3; ++g){
    const f16* wrow = Whh + (size_t)(g*256 + Qg*16 + l16)*256;
#pragma unroll
    for (int kt = 0; kt < 8; ++kt) aW[g][kt] = *(const f16x8*)(wrow + kt*32 + l4*8);
  }

  const f16* gp = gx + (size_t)(b0 + l16)*768;
  f16* ap  = Abuf + (size_t)(b0 + l16)*128*512 + dir*256 + (size_t)(dir ? 127 : 0)*512;
  int  astep = dir ? -512 : 512;
  f16* app = ap;

  const int myoff = l16*256 + wv*32 + l4*8;     // byte offset in my 4KB hx slice
  const int cb = tid >> 5;                      // copy-in: batch 0..15
  const int cc = (tid & 31) * 4;                // copy-in: col-in-half 0..124
  const int poff = (half^1)*128;                // partner cols in a16

  f16x4 pend = (f16x4){(f16)0.f,(f16)0.f,(f16)0.f,(f16)0.f};

  __syncthreads();

#pragma unroll 1
  for (int t = 0; t < 128; ++t){
    // deferred ys store for step t-1
    if (t) *(f16x4*)(app + d0) = pend;

    const f16* rb = &a16[t & 1][l16][l4*8];
    f16x8 bf[8];
#pragma unroll
    for (int kt = 0; kt < 8; ++kt) bf[kt] = *(const f16x8*)(rb + kt*32);

    f16x4 xgr = *(const f16x4*)(gp + 0*256 + d0);
    f16x4 xgz = *(const f16x4*)(gp + 1*256 + d0);
    f16x4 xgn = *(const f16x4*)(gp + 2*256 + d0);

    // phase 1: r,z chains
    f32x4 accr = {0.f,0.f,0.f,0.f}, accz = {0.f,0.f,0.f,0.f};
#pragma unroll
    for (int kt = 0; kt < 8; ++kt){
      accr = __builtin_amdgcn_mfma_f32_16x16x32_f16(aW[0][kt], bf[kt], accr, 0, 0, 0);
      accz = __builtin_amdgcn_mfma_f32_16x16x32_f16(aW[1][kt], bf[kt], accz, 0, 0, 0);
    }
    // phase 2: n chain (sigmoids overlap with it)
    f32x4 accn = {0.f,0.f,0.f,0.f};
#pragma unroll
    for (int kt = 0; kt < 8; ++kt)
      accn = __builtin_amdgcn_mfma_f32_16x16x32_f16(aW[2][kt], bf[kt], accn, 0, 0, 0);

    float rr[4], zz[4];
#pragma unroll
    for (int r = 0; r < 4; ++r){
      rr[r] = fsig((float)xgr[r] + accr[r]);
      zz[r] = fsig((float)xgz[r] + accz[r]);
    }

    int nxt = (t & 1) ^ 1;
    float4 bh4 = *(const float4*)(&bhnL[d0]);
    f16x4 hold = pend;
    f16x4 o4;
#pragma unroll
    for (int r = 0; r < 4; ++r){
      float bh = (r==0)?bh4.x:(r==1)?bh4.y:(r==2)?bh4.z:bh4.w;
      float nn = ftanh((float)xgn[r] + rr[r]*(accn[r] + bh));
      float h2 = nn + zz[r]*((float)hold[r] - nn);
      o4[r] = (f16)h2;
    }
    *(f16x4*)(&a16[nxt][l16][d0]) = o4;           // own half into LDS
    pend = o4;
    app = ap; ap += astep;
    gp += 24576;

    if (t < 127){
      // publish own half to LLC (bypasses L2 -> device-coherent, no flushes)
      __hip_atomic_store((u64*)(hx_mine + (size_t)(t&1)*4096 + myoff),
                         __builtin_bit_cast(u64, o4),
                         __ATOMIC_RELAXED, __HIP_MEMORY_SCOPE_AGENT);
      __syncthreads();   // all waves' hx stores drained (per-wave vmcnt at barrier)
      if (tid == 0)
        __hip_atomic_store(&flags_mine[t], epoch,
                           __ATOMIC_RELEASE, __HIP_MEMORY_SCOPE_AGENT);
      while (__hip_atomic_load(&flags_partner[t],
                               __ATOMIC_ACQUIRE, __HIP_MEMORY_SCOPE_AGENT) != epoch)
        __builtin_amdgcn_s_sleep(2);
      u64 v = __hip_atomic_load((u64*)(hx_partner + (size_t)(t&1)*4096 + cb*256 + cc*2),
                                __ATOMIC_RELAXED, __HIP_MEMORY_SCOPE_AGENT);
      *(u64*)((char*)&a16[nxt][cb][0] + (size_t)(poff + cc)*2) = v;  // partner half -> LDS
      __syncthreads();   // a16[nxt] complete for step t+1
    }
  }
  // final ys store (t = 127)
  *(f16x4*)(app + d0) = pend;
}

// ---------------------------------------------------------------------------
// K4: rnn_out[m][n] = Abuf[m] . W_w[n] + W_b[n]   (K=512; all-f16 operands)
__global__ __launch_bounds__(256) void k_rnnout(const f16* __restrict__ Abuf,
                                                const f16* __restrict__ Ww16,
                                                const float* __restrict__ Wb,
                                                float* __restrict__ rnn){
  int lane = threadIdx.x & 63, wv = threadIdx.x >> 6;
  int l16 = lane & 15, l4 = lane >> 4;
  int mrow = blockIdx.x*64 + wv*16;
  const f16* arow = Abuf + (size_t)(mrow + l16)*512;
  f16x8 af[16];
#pragma unroll
  for (int kt = 0; kt < 16; ++kt) af[kt] = *(const f16x8*)(arow + kt*32 + l4*8);
  for (int nt = 0; nt < 16; ++nt){
    int n = nt*16 + l16;
    const f16* brow = Ww16 + (size_t)n*512;
    f32x4 acc = {0.f,0.f,0.f,0.f};
#pragma unroll
    for (int kt = 0; kt < 16; ++kt){
      f16x8 bf = *(const f16x8*)(brow + kt*32 + l4*8);
      acc = __builtin_amdgcn_mfma_f32_16x16x32_f16(af[kt], bf, acc, 0, 0, 0);
    }
    float bias = Wb[n];
#pragma unroll
    for (int r = 0; r < 4; ++r)
      rnn[(size_t)(mrow + l4*4 + r)*256 + n] = acc[r] + bias;
  }
}

// ---------------------------------------------------------------------------
// K5: hidden/u = concat(hT_f, hT_b) . W_w^T + W_b  via MFMA (M=32,N=256,K=512)
__global__ __launch_bounds__(256) void k_hidden(const f16* __restrict__ Abuf,
                                                const f16* __restrict__ Ww16,
                                                const float* __restrict__ Wb,
                                                float* __restrict__ hidden,
                                                float* __restrict__ u){
  int lane = threadIdx.x & 63, wv = threadIdx.x >> 6;
  int l16 = lane & 15, l4 = lane >> 4;
  int mt = wv & 1, nt = blockIdx.x*2 + (wv >> 1);
  int b = mt*16 + l16;
  const f16* rowf = Abuf + ((size_t)b*128 + 127)*512;
  const f16* rowb = Abuf + ((size_t)b*128)*512;
  f16x8 af[16];
#pragma unroll
  for (int kt = 0; kt < 16; ++kt){
    int k = kt*32 + l4*8;
    af[kt] = *(const f16x8*)((k < 256 ? rowf : rowb) + k);
  }
  int n = nt*16 + l16;
  const f16* brow = Ww16 + (size_t)n*512;
  f32x4 acc = {0.f,0.f,0.f,0.f};
#pragma unroll
  for (int kt = 0; kt < 16; ++kt){
    f16x8 bf = *(const f16x8*)(brow + kt*32 + l4*8);
    acc = __builtin_amdgcn_mfma_f32_16x16x32_f16(af[kt], bf, acc, 0, 0, 0);
  }
  float bias = Wb[n];
#pragma unroll
  for (int r = 0; r < 4; ++r){
    int bo = mt*16 + l4*4 + r;
    float v = acc[r] + bias;
    hidden[(size_t)bo*256 + n] = v;
    u[(size_t)bo*256 + n] = v;
  }
}

// ---------------------------------------------------------------------------
// K6a: logits[b][l] = (sum_m tblA[src[b,l,m]] + lm_add) . u[b]
__global__ __launch_bounds__(256) void k_logits(const int* __restrict__ src,
                                                const int* __restrict__ kbl,
                                                const int* __restrict__ cvl,
                                                const float* __restrict__ tblA,
                                                const float* __restrict__ rnn,
                                                const float* __restrict__ u,
                                                float* __restrict__ logits){
  int b = blockIdx.x >> 5, chunk = blockIdx.x & 31;
  int lane = threadIdx.x & 63, wv = threadIdx.x >> 6;
  int kb = kbl[b], cl = cvl[b];
  float4 uv = *(const float4*)(u + b*256 + lane*4);
#pragma unroll
  for (int i = 0; i < 4; ++i){
    int l = chunk*16 + wv*4 + i;
    const int* sp = src + ((size_t)b*512 + l)*4;
    float b0 = 0.f, b1 = 0.f, b2 = 0.f, b3 = 0.f;
#pragma unroll
    for (int m = 0; m < 4; ++m){
      float4 wq = *(const float4*)(tblA + (size_t)sp[m]*256 + lane*4);
      b0 += wq.x; b1 += wq.y; b2 += wq.z; b3 += wq.w;
    }
    int rel = l - kb;
    if (rel >= 0 && rel < cl){
      int rc = rel < 127 ? rel : 127;
      float4 rv = *(const float4*)(rnn + ((size_t)b*128 + rc)*256 + lane*4);
      b0 += rv.x; b1 += rv.y; b2 += rv.z; b3 += rv.w;
    }
    float p = b0*uv.x + b1*uv.y + b2*uv.z + b3*uv.w;
#pragma unroll
    for (int off = 32; off >= 1; off >>= 1) p += __shfl_down(p, off);
    if (lane == 0) logits[(size_t)b*512 + l] = p;
  }
}

// ---------------------------------------------------------------------------
// K6b: fused softmax + o_k accumulate (256 blocks = (b<<3)|chunk).
__global__ __launch_bounds__(256) void k_okv(const int* __restrict__ src,
                                             const int* __restrict__ kbl,
                                             const int* __restrict__ cvl,
                                             const float* __restrict__ tblC,
                                             const float* __restrict__ rnn,
                                             const float* __restrict__ logits,
                                             float* __restrict__ u,
                                             float* __restrict__ gp_out, int write_gp){
  int b = blockIdx.x >> 3, c = blockIdx.x & 7;
  int d = threadIdx.x, lane = d & 63, wv = d >> 6;
  __shared__ float red[4];
  __shared__ float bc;
  __shared__ float pr[512];
  __shared__ int   sidx[256];

  float v0 = logits[(size_t)b*512 + d];
  float v1 = logits[(size_t)b*512 + 256 + d];
  float m = fmaxf(v0, v1);
#pragma unroll
  for (int off = 32; off >= 1; off >>= 1) m = fmaxf(m, __shfl_down(m, off));
  if (lane == 0) red[wv] = m;
  __syncthreads();
  if (d == 0) bc = fmaxf(fmaxf(red[0], red[1]), fmaxf(red[2], red[3]));
  __syncthreads();
  float mx = bc;
  float e0 = __expf(v0 - mx), e1 = __expf(v1 - mx);
  float s = e0 + e1;
#pragma unroll
  for (int off = 32; off >= 1; off >>= 1) s += __shfl_down(s, off);
  __syncthreads();
  if (lane == 0) red[wv] = s;
  __syncthreads();
  if (d == 0) bc = red[0] + red[1] + red[2] + red[3];
  __syncthreads();
  float inv = 1.0f/bc;
  pr[d] = e0*inv; pr[256 + d] = e1*inv;
  sidx[d] = src[(size_t)b*2048 + c*256 + d];
  if (write_gp && c == 0){
    gp_out[(size_t)b*512 + d]       = fsig(v0);
    gp_out[(size_t)b*512 + 256 + d] = fsig(v1);
  }
  __syncthreads();

  int kb = kbl[b], cl = cvl[b];
  float acc = 0.f;
  for (int l = 0; l < 64; ++l){
    const int* sp = sidx + l*4;
    float bag = tblC[(size_t)sp[0]*256 + d] + tblC[(size_t)sp[1]*256 + d]
              + tblC[(size_t)sp[2]*256 + d] + tblC[(size_t)sp[3]*256 + d];
    int rel = (c*64 + l) - kb;
    if (rel >= 0 && rel < cl){
      int rc = rel < 127 ? rel : 127;
      bag += rnn[((size_t)b*128 + rc)*256 + d];
    }
    acc += pr[c*64 + l] * bag;
  }
  atomicAdd(&u[(size_t)b*256 + d], acc);
}

// ---------------------------------------------------------------------------
// K7: encoded[b][d] = relu(concat(hidden,u) . proj_w[d] + proj_b[d])  (fp32)
__global__ void k_encoded(const float* __restrict__ hidden, const float* __restrict__ u,
                          const float* __restrict__ pw, const float* __restrict__ pb,
                          float* __restrict__ out){
  int b = blockIdx.x, d = threadIdx.x;
  const float* w = pw + (size_t)d*512;
  float s = pb[d];
  for (int k = 0; k < 256; ++k) s += hidden[b*256 + k] * w[k];
  for (int k = 0; k < 256; ++k) s += u[b*256 + k]      * w[256 + k];
  out[(size_t)b*256 + d] = fmaxf(s, 0.f);
}

// ---------------------------------------------------------------------------
extern "C" void kernel_launch(void* const* d_in, const int* in_sizes, int n_in,
                              void* d_out, int out_size, void* d_ws, size_t ws_size,
                              hipStream_t stream){
  (void)in_sizes; (void)n_in; (void)out_size;
  float* out = (float*)d_out;  // [0:16384) global_pointer, [16384:24576) encoded

  const size_t WS_NEEDED = 25034752;                 // base layout
  const size_t EXT_OFF   = 25034752;                 // exchange extension
  const size_t WS_BIG    = EXT_OFF + 135176;         // hx 128K + flags 4K + epoch
  if (ws_size < WS_NEEDED){
    k_zero<<<96, 256, 0, stream>>>(out);
    return;
  }
  bool big = ws_size >= WS_BIG;

  const int* conv  = (const int*)d_in[0];
  const int* src   = (const int*)d_in[1];
  const int* kbl   = (const int*)d_in[2];
  const int* cvl   = (const int*)d_in[3];
  const float* emb_ctx = (const float*)d_in[4];
  const float* Ct      = (const float*)d_in[5];
  const float* Wih_f = (const float*)d_in[6];
  const float* Whh_f = (const float*)d_in[7];
  const float* bih_f = (const float*)d_in[8];
  const float* bhh_f = (const float*)d_in[9];
  const float* Wih_b = (const float*)d_in[10];
  const float* Whh_b = (const float*)d_in[11];
  const float* bih_b = (const float*)d_in[12];
  const float* bhh_b = (const float*)d_in[13];
  const float* Ww = (const float*)d_in[14];
  const float* Wb = (const float*)d_in[15];
  const float* pw = (const float*)d_in[16];
  const float* pb = (const float*)d_in[17];

  char* ws = (char*)d_ws;
  f16*   emb    = (f16*)(ws);                  //  2,097,152  [4096][256] f16
  f16*   gx_f   = (f16*)(ws + 2097152);        //  6,291,456  [t*32+b][768] f16
  f16*   gx_b   = (f16*)(ws + 8388608);        //  6,291,456
  f16*   Abuf   = (f16*)(ws + 14680064);       //  4,194,304  [b*128+t][512] f16
  float* rnn    = (float*)(ws + 18874368);     //  4,194,304  [b*128+t][256] f32
  float* hidden = (float*)(ws + 23068672);     //     32,768
  float* u      = (float*)(ws + 23101440);     //     32,768
  float* logits = (float*)(ws + 23134208);     //     65,536
  f16*   wihf16 = (f16*)(ws + 23199744);       //    393,216  [768][256]
  f16*   wihb16 = (f16*)(ws + 23592960);       //    393,216
  f16*   whhf16 = (f16*)(ws + 23986176);       //    393,216
  f16*   whhb16 = (f16*)(ws + 24379392);       //    393,216
  f16*   ww16   = (f16*)(ws + 24772608);       //    262,144  [256][512]
  char*  ext    = ws + EXT_OFF;                // [hx 131072][flags 4096][epoch 4]
  unsigned* epoch = big ? (unsigned*)(ext + 135168) : nullptr;

  k_cvtall<<<768, 256, 0, stream>>>(Wih_f, Wih_b, Whh_f, Whh_b, Ww,
                                    wihf16, wihb16, whhf16, whhb16, ww16, epoch);
  k_embbag<<<4096, 256, 0, stream>>>(conv, emb_ctx, emb);
  k_gx<<<64, 256, 0, stream>>>(emb, wihf16, bih_f, bhh_f, gx_f, 0);
  k_gx<<<64, 256, 0, stream>>>(emb, wihb16, bih_b, bhh_b, gx_b, 1);
  if (big)
    k_gru_duo<<<8, 512, 0, stream>>>(gx_f, gx_b, whhf16, whhb16, bhh_f, bhh_b, Abuf, ext);
  else
    k_gru_solo<<<4, 512, 0, stream>>>(gx_f, gx_b, whhf16, whhb16, bhh_f, bhh_b, Abuf);
  k_rnnout<<<64, 256, 0, stream>>>(Abuf, ww16, Wb, rnn);
  k_hidden<<<8, 256, 0, stream>>>(Abuf, ww16, Wb, hidden, u);

  for (int hop = 0; hop < 3; ++hop){
    const float* tA = Ct + (size_t)hop     * 32000 * 256;
    const float* tC = Ct + (size_t)(hop+1) * 32000 * 256;
    k_logits<<<1024, 256, 0, stream>>>(src, kbl, cvl, tA, rnn, u, logits);
    k_okv<<<256, 256, 0, stream>>>(src, kbl, cvl, tC, rnn, logits, u,
                                   out, hop == 2 ? 1 : 0);
  }
  k_encoded<<<32, 256, 0, stream>>>(hidden, u, pw, pb, out + 16384);
}

// Round 6
// 848.456 us; speedup vs baseline: 1.2639x; 1.2639x over previous
//
#include <hip/hip_runtime.h>

typedef _Float16 f16;
typedef _Float16 f16x8 __attribute__((ext_vector_type(8)));
typedef _Float16 f16x4 __attribute__((ext_vector_type(4)));
typedef float    f32x4 __attribute__((ext_vector_type(4)));

// Problem constants: B=32, T=128, L=512, D=256, M=4, VOCAB=32000, HOPS=3
// DTYPE: ALL float inputs/outputs are fp32.

__device__ __forceinline__ float frcp(float x){
  float r; asm("v_rcp_f32 %0, %1" : "=v"(r) : "v"(x)); return r;
}
__device__ __forceinline__ float fsig(float x){ return frcp(1.0f + __expf(-x)); }
__device__ __forceinline__ float ftanh(float x){ return 2.0f*frcp(1.0f + __expf(-2.0f*x)) - 1.0f; }

// ---------------------------------------------------------------------------
__global__ void k_zero(float* out){
  int i = blockIdx.x*256 + threadIdx.x;
  if (i < 24576) out[i] = 0.f;
}

// ---------------------------------------------------------------------------
// K0: one-shot fp32 -> f16 conversion of ALL five weight matrices (one launch)
__global__ void k_cvtall(const float* __restrict__ s0, const float* __restrict__ s1,
                         const float* __restrict__ s2, const float* __restrict__ s3,
                         const float* __restrict__ s4,
                         f16* __restrict__ d0, f16* __restrict__ d1,
                         f16* __restrict__ d2, f16* __restrict__ d3,
                         f16* __restrict__ d4){
  int i = blockIdx.x*256 + threadIdx.x;          // grid covers 196608
  d0[i] = (f16)s0[i];                            // Wih_f  [768*256]
  d1[i] = (f16)s1[i];                            // Wih_b
  d2[i] = (f16)s2[i];                            // Whh_f
  d3[i] = (f16)s3[i];                            // Whh_b
  if (i < 131072) d4[i] = (f16)s4[i];            // W_w    [256*512]
}

// ---------------------------------------------------------------------------
// K1: embed-bag: emb[b*128+t][d] = sum_m emb_ctx[conv[b,t,m]][d]  (f16 out)
__global__ void k_embbag(const int* __restrict__ conv, const float* __restrict__ tbl,
                         f16* __restrict__ emb){
  int bt = blockIdx.x, d = threadIdx.x;
  const int* ix = conv + (size_t)bt*4;
  float s = 0.f;
#pragma unroll
  for (int m = 0; m < 4; ++m) s += tbl[(size_t)ix[m]*256 + d];
  emb[(size_t)bt*256 + d] = (f16)s;
}

// ---------------------------------------------------------------------------
// K2: gx[m=t*32+b][j] = emb_row . Wih[j] + bih[j] + (j<512 ? bhh[j] : 0)
__global__ __launch_bounds__(256) void k_gx(const f16* __restrict__ emb,
                                            const f16* __restrict__ W16,
                                            const float* __restrict__ bih,
                                            const float* __restrict__ bhh,
                                            f16* __restrict__ gx, int rev){
  int lane = threadIdx.x & 63, wv = threadIdx.x >> 6;
  int l16 = lane & 15, l4 = lane >> 4;
  int mrow = blockIdx.x*64 + wv*16;
  int m = mrow + l16;
  int t = m >> 5, b = m & 31;
  int tsrc = rev ? (127 - t) : t;
  const f16* arow = emb + (size_t)(b*128 + tsrc)*256;
  f16x8 af[8];
#pragma unroll
  for (int kt = 0; kt < 8; ++kt) af[kt] = *(const f16x8*)(arow + kt*32 + l4*8);

  for (int nt = 0; nt < 48; ++nt){
    int n = nt*16 + l16;
    const f16* brow = W16 + (size_t)n*256;   // B[k][n] = Wih[n][k]
    f32x4 acc = {0.f,0.f,0.f,0.f};
#pragma unroll
    for (int kt = 0; kt < 8; ++kt){
      f16x8 bf = *(const f16x8*)(brow + kt*32 + l4*8);
      acc = __builtin_amdgcn_mfma_f32_16x16x32_f16(af[kt], bf, acc, 0, 0, 0);
    }
    float bias = bih[n] + (n < 512 ? bhh[n] : 0.f);
#pragma unroll
    for (int r = 0; r < 4; ++r){
      int m2 = mrow + l4*4 + r;
      gx[(size_t)m2*768 + n] = (f16)(acc[r] + bias);
    }
  }
}

// ---------------------------------------------------------------------------
// K3: GRU recurrence (round-3 proven: 344 us, VALU 0.53, MfmaUtil 0.36).
// Round-5 post-mortem: the gate-split duo (cross-block LLC handshake/step)
// measured 509 us — sync cost > halved-MFMA gain; refuted, removed.
// Residency analysis (rounds 2-4): weights live in AGPRs; unified VGPR/AGPR
// budget means residency requires <=2 waves/SIMD -> 512 threads, lb(512,1).
__global__ __launch_bounds__(512, 1) void k_gru(const f16* __restrict__ gx_f,
                                                const f16* __restrict__ gx_b,
                                                const f16* __restrict__ whhf16,
                                                const f16* __restrict__ whhb16,
                                                const float* __restrict__ bhh_f,
                                                const float* __restrict__ bhh_b,
                                                f16* __restrict__ Abuf){
  int dir = blockIdx.x >> 1, grp = blockIdx.x & 1, b0 = grp*16;
  const f16*   gx  = dir ? gx_b   : gx_f;
  const f16*   Whh = dir ? whhb16 : whhf16;
  const float* bhh = dir ? bhh_b  : bhh_f;

  int tid = threadIdx.x, lane = tid & 63, wv = tid >> 6;
  int l16 = lane & 15, l4 = lane >> 4;

  __shared__ __align__(16) f16   a16[2][16][264];
  __shared__ __align__(16) float bhnL[256];
  for (int i = tid; i < (16*264*2)/4; i += 512) ((unsigned*)&a16[0][0][0])[i] = 0u;
  if (tid < 256) bhnL[tid] = bhh[512 + tid];

  f16x8 aW[2][3][8];
#pragma unroll
  for (int q = 0; q < 2; ++q){
    int Q = 2*wv + q;
#pragma unroll
    for (int g = 0; g < 3; ++g){
      const f16* wrow = Whh + (size_t)(g*256 + Q*16 + l16)*256;
#pragma unroll
      for (int kt = 0; kt < 8; ++kt) aW[q][g][kt] = *(const f16x8*)(wrow + kt*32 + l4*8);
    }
  }

  const f16* gp = gx + (size_t)(b0 + l16)*768;
  f16* ap  = Abuf + (size_t)(b0 + l16)*128*512 + dir*256 + (size_t)(dir ? 127 : 0)*512;
  int  astep = dir ? -512 : 512;
  f16* app = ap;

  const int d00 = (2*wv    )*16 + l4*4;
  const int d01 = (2*wv + 1)*16 + l4*4;

  f16x4 pend[2];
  pend[0] = (f16x4){(f16)0.f,(f16)0.f,(f16)0.f,(f16)0.f};
  pend[1] = (f16x4){(f16)0.f,(f16)0.f,(f16)0.f,(f16)0.f};

  __syncthreads();

#pragma unroll 1
  for (int t = 0; t < 128; ++t){
    if (t){
      *(f16x4*)(app + d00) = pend[0];
      *(f16x4*)(app + d01) = pend[1];
    }
    f16x4 xg[2][3];
#pragma unroll
    for (int q = 0; q < 2; ++q)
#pragma unroll
      for (int g = 0; g < 3; ++g)
        xg[q][g] = *(const f16x4*)(gp + g*256 + (2*wv+q)*16 + l4*4);

    const f16* rb = &a16[t & 1][l16][l4*8];

    f32x4 accr[2], accz[2];
#pragma unroll
    for (int q = 0; q < 2; ++q){ accr[q] = (f32x4){0.f,0.f,0.f,0.f};
                                 accz[q] = (f32x4){0.f,0.f,0.f,0.f}; }
#pragma unroll
    for (int kt = 0; kt < 8; ++kt){
      f16x8 bf = *(const f16x8*)(rb + kt*32);
#pragma unroll
      for (int q = 0; q < 2; ++q){
        accr[q] = __builtin_amdgcn_mfma_f32_16x16x32_f16(aW[q][0][kt], bf, accr[q], 0, 0, 0);
        accz[q] = __builtin_amdgcn_mfma_f32_16x16x32_f16(aW[q][1][kt], bf, accz[q], 0, 0, 0);
      }
    }
    f32x4 accn[2];
#pragma unroll
    for (int q = 0; q < 2; ++q) accn[q] = (f32x4){0.f,0.f,0.f,0.f};
#pragma unroll
    for (int kt = 0; kt < 8; ++kt){
      f16x8 bf = *(const f16x8*)(rb + kt*32);
#pragma unroll
      for (int q = 0; q < 2; ++q)
        accn[q] = __builtin_amdgcn_mfma_f32_16x16x32_f16(aW[q][2][kt], bf, accn[q], 0, 0, 0);
    }
    float rr[2][4], zz[2][4];
#pragma unroll
    for (int q = 0; q < 2; ++q)
#pragma unroll
      for (int r = 0; r < 4; ++r){
        rr[q][r] = fsig((float)xg[q][0][r] + accr[q][r]);
        zz[q][r] = fsig((float)xg[q][1][r] + accz[q][r]);
      }
    int nxt = (t & 1) ^ 1;
#pragma unroll
    for (int q = 0; q < 2; ++q){
      int d0 = (2*wv+q)*16 + l4*4;
      float4 bh4 = *(const float4*)(&bhnL[d0]);
      f16x4 hold = pend[q];
      f16x4 o4;
#pragma unroll
      for (int r = 0; r < 4; ++r){
        float bh = (r==0)?bh4.x:(r==1)?bh4.y:(r==2)?bh4.z:bh4.w;
        float nn = ftanh((float)xg[q][2][r] + rr[q][r]*(accn[q][r] + bh));
        float h2 = nn + zz[q][r]*((float)hold[r] - nn);
        o4[r] = (f16)h2;
      }
      *(f16x4*)(&a16[nxt][l16][d0]) = o4;
      pend[q] = o4;
    }
    app = ap; ap += astep;
    gp += 24576;
    __syncthreads();
  }
  *(f16x4*)(app + d00) = pend[0];
  *(f16x4*)(app + d01) = pend[1];
}

// ---------------------------------------------------------------------------
// K4: rnn_out[m][n] = Abuf[m] . W_w[n] + W_b[n]   (K=512; all-f16 operands)
__global__ __launch_bounds__(256) void k_rnnout(const f16* __restrict__ Abuf,
                                                const f16* __restrict__ Ww16,
                                                const float* __restrict__ Wb,
                                                float* __restrict__ rnn){
  int lane = threadIdx.x & 63, wv = threadIdx.x >> 6;
  int l16 = lane & 15, l4 = lane >> 4;
  int mrow = blockIdx.x*64 + wv*16;
  const f16* arow = Abuf + (size_t)(mrow + l16)*512;
  f16x8 af[16];
#pragma unroll
  for (int kt = 0; kt < 16; ++kt) af[kt] = *(const f16x8*)(arow + kt*32 + l4*8);
  for (int nt = 0; nt < 16; ++nt){
    int n = nt*16 + l16;
    const f16* brow = Ww16 + (size_t)n*512;
    f32x4 acc = {0.f,0.f,0.f,0.f};
#pragma unroll
    for (int kt = 0; kt < 16; ++kt){
      f16x8 bf = *(const f16x8*)(brow + kt*32 + l4*8);
      acc = __builtin_amdgcn_mfma_f32_16x16x32_f16(af[kt], bf, acc, 0, 0, 0);
    }
    float bias = Wb[n];
#pragma unroll
    for (int r = 0; r < 4; ++r)
      rnn[(size_t)(mrow + l4*4 + r)*256 + n] = acc[r] + bias;
  }
}

// ---------------------------------------------------------------------------
// K5: hidden/u = concat(hT_f, hT_b) . W_w^T + W_b  via MFMA (M=32,N=256,K=512)
__global__ __launch_bounds__(256) void k_hidden(const f16* __restrict__ Abuf,
                                                const f16* __restrict__ Ww16,
                                                const float* __restrict__ Wb,
                                                float* __restrict__ hidden,
                                                float* __restrict__ u){
  int lane = threadIdx.x & 63, wv = threadIdx.x >> 6;
  int l16 = lane & 15, l4 = lane >> 4;
  int mt = wv & 1, nt = blockIdx.x*2 + (wv >> 1);
  int b = mt*16 + l16;
  const f16* rowf = Abuf + ((size_t)b*128 + 127)*512;
  const f16* rowb = Abuf + ((size_t)b*128)*512;
  f16x8 af[16];
#pragma unroll
  for (int kt = 0; kt < 16; ++kt){
    int k = kt*32 + l4*8;
    af[kt] = *(const f16x8*)((k < 256 ? rowf : rowb) + k);
  }
  int n = nt*16 + l16;
  const f16* brow = Ww16 + (size_t)n*512;
  f32x4 acc = {0.f,0.f,0.f,0.f};
#pragma unroll
  for (int kt = 0; kt < 16; ++kt){
    f16x8 bf = *(const f16x8*)(brow + kt*32 + l4*8);
    acc = __builtin_amdgcn_mfma_f32_16x16x32_f16(af[kt], bf, acc, 0, 0, 0);
  }
  float bias = Wb[n];
#pragma unroll
  for (int r = 0; r < 4; ++r){
    int bo = mt*16 + l4*4 + r;
    float v = acc[r] + bias;
    hidden[(size_t)bo*256 + n] = v;
    u[(size_t)bo*256 + n] = v;
  }
}

// ---------------------------------------------------------------------------
// K6a: logits[b][l] = bagA[b][l] . u[b].
// Round-6 change: hop h's bagA (gather of C_tables[h] + lm-add) is IDENTICAL
// to what hop h-1's k_okv already computed — okv stores it (f16) into bagbuf
// and hops 1,2 read 8.4 MB sequentially instead of re-gathering 64 MB random.
__global__ __launch_bounds__(256) void k_logits(const int* __restrict__ src,
                                                const int* __restrict__ kbl,
                                                const int* __restrict__ cvl,
                                                const float* __restrict__ tblA,
                                                const float* __restrict__ rnn,
                                                const float* __restrict__ u,
                                                float* __restrict__ logits,
                                                const f16* __restrict__ bagin){
  int b = blockIdx.x >> 5, chunk = blockIdx.x & 31;
  int lane = threadIdx.x & 63, wv = threadIdx.x >> 6;
  float4 uv = *(const float4*)(u + b*256 + lane*4);
  if (bagin){
#pragma unroll
    for (int i = 0; i < 4; ++i){
      int l = chunk*16 + wv*4 + i;
      f16x4 bv = *(const f16x4*)(bagin + ((size_t)b*512 + l)*256 + lane*4);
      float p = (float)bv[0]*uv.x + (float)bv[1]*uv.y
              + (float)bv[2]*uv.z + (float)bv[3]*uv.w;
#pragma unroll
      for (int off = 32; off >= 1; off >>= 1) p += __shfl_down(p, off);
      if (lane == 0) logits[(size_t)b*512 + l] = p;
    }
    return;
  }
  int kb = kbl[b], cl = cvl[b];
#pragma unroll
  for (int i = 0; i < 4; ++i){
    int l = chunk*16 + wv*4 + i;
    const int* sp = src + ((size_t)b*512 + l)*4;
    float b0 = 0.f, b1 = 0.f, b2 = 0.f, b3 = 0.f;
#pragma unroll
    for (int m = 0; m < 4; ++m){
      float4 wq = *(const float4*)(tblA + (size_t)sp[m]*256 + lane*4);
      b0 += wq.x; b1 += wq.y; b2 += wq.z; b3 += wq.w;
    }
    int rel = l - kb;
    if (rel >= 0 && rel < cl){
      int rc = rel < 127 ? rel : 127;
      float4 rv = *(const float4*)(rnn + ((size_t)b*128 + rc)*256 + lane*4);
      b0 += rv.x; b1 += rv.y; b2 += rv.z; b3 += rv.w;
    }
    float p = b0*uv.x + b1*uv.y + b2*uv.z + b3*uv.w;
#pragma unroll
    for (int off = 32; off >= 1; off >>= 1) p += __shfl_down(p, off);
    if (lane == 0) logits[(size_t)b*512 + l] = p;
  }
}

// ---------------------------------------------------------------------------
// K6b: fused softmax + o_k accumulate. 512 blocks = (b<<4)|chunk (16 chunks of
// 32 l -> 2 blocks/CU for gather concurrency); each block redundantly computes
// the 512-wide softmax (cheap), accumulates u[b][d] += sum_l prob*bag via
// atomicAdd, and (if bagout) stores bag f16 for next hop's k_logits.
__global__ __launch_bounds__(256) void k_okv(const int* __restrict__ src,
                                             const int* __restrict__ kbl,
                                             const int* __restrict__ cvl,
                                             const float* __restrict__ tblC,
                                             const float* __restrict__ rnn,
                                             const float* __restrict__ logits,
                                             float* __restrict__ u,
                                             float* __restrict__ gp_out, int write_gp,
                                             f16* __restrict__ bagout){
  int b = blockIdx.x >> 4, c = blockIdx.x & 15;
  int d = threadIdx.x, lane = d & 63, wv = d >> 6;
  __shared__ float red[4];
  __shared__ float bc;
  __shared__ float pr[512];
  __shared__ int   sidx[128];

  float v0 = logits[(size_t)b*512 + d];
  float v1 = logits[(size_t)b*512 + 256 + d];
  float m = fmaxf(v0, v1);
#pragma unroll
  for (int off = 32; off >= 1; off >>= 1) m = fmaxf(m, __shfl_down(m, off));
  if (lane == 0) red[wv] = m;
  __syncthreads();
  if (d == 0) bc = fmaxf(fmaxf(red[0], red[1]), fmaxf(red[2], red[3]));
  __syncthreads();
  float mx = bc;
  float e0 = __expf(v0 - mx), e1 = __expf(v1 - mx);
  float s = e0 + e1;
#pragma unroll
  for (int off = 32; off >= 1; off >>= 1) s += __shfl_down(s, off);
  __syncthreads();
  if (lane == 0) red[wv] = s;
  __syncthreads();
  if (d == 0) bc = red[0] + red[1] + red[2] + red[3];
  __syncthreads();
  float inv = 1.0f/bc;
  pr[d] = e0*inv; pr[256 + d] = e1*inv;
  if (d < 128) sidx[d] = src[(size_t)b*2048 + c*128 + d];
  if (write_gp && c == 0){
    gp_out[(size_t)b*512 + d]       = fsig(v0);
    gp_out[(size_t)b*512 + 256 + d] = fsig(v1);
  }
  __syncthreads();

  int kb = kbl[b], cl = cvl[b];
  float acc = 0.f;
  for (int l = 0; l < 32; ++l){
    const int* sp = sidx + l*4;
    float bag = tblC[(size_t)sp[0]*256 + d] + tblC[(size_t)sp[1]*256 + d]
              + tblC[(size_t)sp[2]*256 + d] + tblC[(size_t)sp[3]*256 + d];
    int rel = (c*32 + l) - kb;
    if (rel >= 0 && rel < cl){
      int rc = rel < 127 ? rel : 127;
      bag += rnn[((size_t)b*128 + rc)*256 + d];
    }
    if (bagout) bagout[((size_t)b*512 + c*32 + l)*256 + d] = (f16)bag;
    acc += pr[c*32 + l] * bag;
  }
  atomicAdd(&u[(size_t)b*256 + d], acc);
}

// ---------------------------------------------------------------------------
// K7: encoded[b][d] = relu(concat(hidden,u) . proj_w[d] + proj_b[d])  (fp32)
__global__ void k_encoded(const float* __restrict__ hidden, const float* __restrict__ u,
                          const float* __restrict__ pw, const float* __restrict__ pb,
                          float* __restrict__ out){
  int b = blockIdx.x, d = threadIdx.x;
  const float* w = pw + (size_t)d*512;
  float s = pb[d];
  for (int k = 0; k < 256; ++k) s += hidden[b*256 + k] * w[k];
  for (int k = 0; k < 256; ++k) s += u[b*256 + k]      * w[256 + k];
  out[(size_t)b*256 + d] = fmaxf(s, 0.f);
}

// ---------------------------------------------------------------------------
extern "C" void kernel_launch(void* const* d_in, const int* in_sizes, int n_in,
                              void* d_out, int out_size, void* d_ws, size_t ws_size,
                              hipStream_t stream){
  (void)in_sizes; (void)n_in; (void)out_size;
  float* out = (float*)d_out;  // [0:16384) global_pointer, [16384:24576) encoded

  const size_t WS_NEEDED = 25034752;
  if (ws_size < WS_NEEDED){
    k_zero<<<96, 256, 0, stream>>>(out);
    return;
  }

  const int* conv  = (const int*)d_in[0];
  const int* src   = (const int*)d_in[1];
  const int* kbl   = (const int*)d_in[2];
  const int* cvl   = (const int*)d_in[3];
  const float* emb_ctx = (const float*)d_in[4];
  const float* Ct      = (const float*)d_in[5];
  const float* Wih_f = (const float*)d_in[6];
  const float* Whh_f = (const float*)d_in[7];
  const float* bih_f = (const float*)d_in[8];
  const float* bhh_f = (const float*)d_in[9];
  const float* Wih_b = (const float*)d_in[10];
  const float* Whh_b = (const float*)d_in[11];
  const float* bih_b = (const float*)d_in[12];
  const float* bhh_b = (const float*)d_in[13];
  const float* Ww = (const float*)d_in[14];
  const float* Wb = (const float*)d_in[15];
  const float* pw = (const float*)d_in[16];
  const float* pb = (const float*)d_in[17];

  char* ws = (char*)d_ws;
  f16*   emb    = (f16*)(ws);                  //  2,097,152  [4096][256] f16
  f16*   gx_f   = (f16*)(ws + 2097152);        //  6,291,456  [t*32+b][768] f16
  f16*   gx_b   = (f16*)(ws + 8388608);        //  6,291,456
  f16*   Abuf   = (f16*)(ws + 14680064);       //  4,194,304  [b*128+t][512] f16
  float* rnn    = (float*)(ws + 18874368);     //  4,194,304  [b*128+t][256] f32
  float* hidden = (float*)(ws + 23068672);     //     32,768
  float* u      = (float*)(ws + 23101440);     //     32,768
  float* logits = (float*)(ws + 23134208);     //     65,536
  f16*   wihf16 = (f16*)(ws + 23199744);       //    393,216  [768][256]
  f16*   wihb16 = (f16*)(ws + 23592960);       //    393,216
  f16*   whhf16 = (f16*)(ws + 23986176);       //    393,216
  f16*   whhb16 = (f16*)(ws + 24379392);       //    393,216
  f16*   ww16   = (f16*)(ws + 24772608);       //    262,144  [256][512]
                                               // end 25,034,752
  // bagbuf (8,388,608 B = [32][512][256] f16) reuses the gx_f/gx_b region,
  // which is dead after k_gru.
  f16*   bagbuf = (f16*)(ws + 2097152);

  k_cvtall<<<768, 256, 0, stream>>>(Wih_f, Wih_b, Whh_f, Whh_b, Ww,
                                    wihf16, wihb16, whhf16, whhb16, ww16);
  k_embbag<<<4096, 256, 0, stream>>>(conv, emb_ctx, emb);
  k_gx<<<64, 256, 0, stream>>>(emb, wihf16, bih_f, bhh_f, gx_f, 0);
  k_gx<<<64, 256, 0, stream>>>(emb, wihb16, bih_b, bhh_b, gx_b, 1);
  k_gru<<<4, 512, 0, stream>>>(gx_f, gx_b, whhf16, whhb16, bhh_f, bhh_b, Abuf);
  k_rnnout<<<64, 256, 0, stream>>>(Abuf, ww16, Wb, rnn);
  k_hidden<<<8, 256, 0, stream>>>(Abuf, ww16, Wb, hidden, u);

  for (int hop = 0; hop < 3; ++hop){
    const float* tA = Ct + (size_t)hop     * 32000 * 256;
    const float* tC = Ct + (size_t)(hop+1) * 32000 * 256;
    k_logits<<<1024, 256, 0, stream>>>(src, kbl, cvl, tA, rnn, u, logits,
                                       hop ? bagbuf : (const f16*)nullptr);
    k_okv<<<512, 256, 0, stream>>>(src, kbl, cvl, tC, rnn, logits, u,
                                   out, hop == 2 ? 1 : 0,
                                   hop < 2 ? bagbuf : (f16*)nullptr);
  }
  k_encoded<<<32, 256, 0, stream>>>(hidden, u, pw, pb, out + 16384);
}

// Round 7
// 745.276 us; speedup vs baseline: 1.4388x; 1.1384x over previous
//
#include <hip/hip_runtime.h>

typedef _Float16 f16;
typedef _Float16 f16x8 __attribute__((ext_vector_type(8)));
typedef _Float16 f16x4 __attribute__((ext_vector_type(4)));
typedef float    f32x4 __attribute__((ext_vector_type(4)));

// Problem constants: B=32, T=128, L=512, D=256, M=4, VOCAB=32000, HOPS=3
// DTYPE: ALL float inputs/outputs are fp32.

__device__ __forceinline__ float frcp(float x){
  float r; asm("v_rcp_f32 %0, %1" : "=v"(r) : "v"(x)); return r;
}
__device__ __forceinline__ float fsig(float x){ return frcp(1.0f + __expf(-x)); }
__device__ __forceinline__ float ftanh(float x){ return 2.0f*frcp(1.0f + __expf(-2.0f*x)) - 1.0f; }

// ---------------------------------------------------------------------------
__global__ void k_zero(float* out){
  int i = blockIdx.x*256 + threadIdx.x;
  if (i < 24576) out[i] = 0.f;
}

// ---------------------------------------------------------------------------
// K0: merged weight-convert (blocks 0..767) + embed-bag (blocks 768..4863).
__global__ __launch_bounds__(256) void k_prep(const float* __restrict__ s0,
                                              const float* __restrict__ s1,
                                              const float* __restrict__ s2,
                                              const float* __restrict__ s3,
                                              const float* __restrict__ s4,
                                              f16* __restrict__ d0, f16* __restrict__ d1,
                                              f16* __restrict__ d2, f16* __restrict__ d3,
                                              f16* __restrict__ d4,
                                              const int* __restrict__ conv,
                                              const float* __restrict__ tbl,
                                              f16* __restrict__ emb){
  int bid = blockIdx.x;
  if (bid < 768){
    int i = bid*256 + threadIdx.x;               // < 196608
    d0[i] = (f16)s0[i];                          // Wih_f  [768*256]
    d1[i] = (f16)s1[i];                          // Wih_b
    d2[i] = (f16)s2[i];                          // Whh_f
    d3[i] = (f16)s3[i];                          // Whh_b
    if (i < 131072) d4[i] = (f16)s4[i];          // W_w    [256*512]
    return;
  }
  int bt = bid - 768, d = threadIdx.x;           // embed-bag
  const int* ix = conv + (size_t)bt*4;
  float s = 0.f;
#pragma unroll
  for (int m = 0; m < 4; ++m) s += tbl[(size_t)ix[m]*256 + d];
  emb[(size_t)bt*256 + d] = (f16)s;
}

// ---------------------------------------------------------------------------
// K2: both directions in one launch: rev = blockIdx>>6, tile = blockIdx&63.
__global__ __launch_bounds__(256) void k_gx2(const f16* __restrict__ emb,
                                             const f16* __restrict__ wf,
                                             const f16* __restrict__ wb,
                                             const float* __restrict__ bih_f,
                                             const float* __restrict__ bhh_f,
                                             const float* __restrict__ bih_b,
                                             const float* __restrict__ bhh_b,
                                             f16* __restrict__ gx_f,
                                             f16* __restrict__ gx_b){
  int rev = blockIdx.x >> 6, blk = blockIdx.x & 63;
  const f16* W16 = rev ? wb : wf;
  const float* bih = rev ? bih_b : bih_f;
  const float* bhh = rev ? bhh_b : bhh_f;
  f16* gx = rev ? gx_b : gx_f;

  int lane = threadIdx.x & 63, wv = threadIdx.x >> 6;
  int l16 = lane & 15, l4 = lane >> 4;
  int mrow = blk*64 + wv*16;
  int m = mrow + l16;
  int t = m >> 5, b = m & 31;
  int tsrc = rev ? (127 - t) : t;
  const f16* arow = emb + (size_t)(b*128 + tsrc)*256;
  f16x8 af[8];
#pragma unroll
  for (int kt = 0; kt < 8; ++kt) af[kt] = *(const f16x8*)(arow + kt*32 + l4*8);

  for (int nt = 0; nt < 48; ++nt){
    int n = nt*16 + l16;
    const f16* brow = W16 + (size_t)n*256;   // B[k][n] = Wih[n][k]
    f32x4 acc = {0.f,0.f,0.f,0.f};
#pragma unroll
    for (int kt = 0; kt < 8; ++kt){
      f16x8 bf = *(const f16x8*)(brow + kt*32 + l4*8);
      acc = __builtin_amdgcn_mfma_f32_16x16x32_f16(af[kt], bf, acc, 0, 0, 0);
    }
    float bias = bih[n] + (n < 512 ? bhh[n] : 0.f);
#pragma unroll
    for (int r = 0; r < 4; ++r){
      int m2 = mrow + l4*4 + r;
      gx[(size_t)m2*768 + n] = (f16)(acc[r] + bias);
    }
  }
}

// ---------------------------------------------------------------------------
// K3: GRU (blocks 0-3, proven 344-us body) + CONCURRENT bagT gathers
// (blocks 4..4+64*ntab). The gathers (raw sum of 4 C_tables rows per (b,l),
// f16 out) depend only on src/C_tables, so they run on the ~252 CUs the GRU
// leaves idle. rnn/lm-add is applied inline later by k_logits/k_okv.
// GRU structure notes (r2-r6): weights live in AGPRs; unified VGPR/AGPR file
// means full residency caps at 2 waves/SIMD (512-reg file) -> lb(512,1);
// 4-wave (r4) and cross-CU split (r5) both measured worse.
__global__ __launch_bounds__(512, 1) void k_grumega(const f16* __restrict__ gx_f,
                                                    const f16* __restrict__ gx_b,
                                                    const f16* __restrict__ whhf16,
                                                    const f16* __restrict__ whhb16,
                                                    const float* __restrict__ bhh_f,
                                                    const float* __restrict__ bhh_b,
                                                    f16* __restrict__ Abuf,
                                                    const int* __restrict__ src,
                                                    const float* __restrict__ Ct,
                                                    f16* __restrict__ bagT,
                                                    int tab0, int tab1, int tab2, int tab3){
  int bid = blockIdx.x;
  if (bid >= 4){
    // ---- gather block: 256 (b,l) tasks, 2 rows per iteration ----
    int gi = bid - 4;
    int slot = gi >> 6;
    int tab = slot == 0 ? tab0 : slot == 1 ? tab1 : slot == 2 ? tab2 : tab3;
    const float* tbl = Ct + (size_t)tab * 32000 * 256;
    f16* dst = bagT + (size_t)slot * 4194304;       // 16384*256 f16
    int tid = threadIdx.x;
    int d = tid & 255, half = tid >> 8;
    int base = (gi & 63) * 256;
#pragma unroll 2
    for (int it = 0; it < 128; ++it){
      int task = base + it*2 + half;                // b*512 + l
      int4 ix = *(const int4*)(src + (size_t)task*4);
      float s = tbl[(size_t)ix.x*256 + d] + tbl[(size_t)ix.y*256 + d]
              + tbl[(size_t)ix.z*256 + d] + tbl[(size_t)ix.w*256 + d];
      dst[(size_t)task*256 + d] = (f16)s;
    }
    return;
  }

  // ---- GRU block (verbatim proven body) ----
  int dir = bid >> 1, grp = bid & 1, b0 = grp*16;
  const f16*   gx  = dir ? gx_b   : gx_f;
  const f16*   Whh = dir ? whhb16 : whhf16;
  const float* bhh = dir ? bhh_b  : bhh_f;

  int tid = threadIdx.x, lane = tid & 63, wv = tid >> 6;
  int l16 = lane & 15, l4 = lane >> 4;

  __shared__ __align__(16) f16   a16[2][16][264];
  __shared__ __align__(16) float bhnL[256];
  for (int i = tid; i < (16*264*2)/4; i += 512) ((unsigned*)&a16[0][0][0])[i] = 0u;
  if (tid < 256) bhnL[tid] = bhh[512 + tid];

  f16x8 aW[2][3][8];
#pragma unroll
  for (int q = 0; q < 2; ++q){
    int Q = 2*wv + q;
#pragma unroll
    for (int g = 0; g < 3; ++g){
      const f16* wrow = Whh + (size_t)(g*256 + Q*16 + l16)*256;
#pragma unroll
      for (int kt = 0; kt < 8; ++kt) aW[q][g][kt] = *(const f16x8*)(wrow + kt*32 + l4*8);
    }
  }

  const f16* gp = gx + (size_t)(b0 + l16)*768;
  f16* ap  = Abuf + (size_t)(b0 + l16)*128*512 + dir*256 + (size_t)(dir ? 127 : 0)*512;
  int  astep = dir ? -512 : 512;
  f16* app = ap;

  const int d00 = (2*wv    )*16 + l4*4;
  const int d01 = (2*wv + 1)*16 + l4*4;

  f16x4 pend[2];
  pend[0] = (f16x4){(f16)0.f,(f16)0.f,(f16)0.f,(f16)0.f};
  pend[1] = (f16x4){(f16)0.f,(f16)0.f,(f16)0.f,(f16)0.f};

  __syncthreads();

#pragma unroll 1
  for (int t = 0; t < 128; ++t){
    if (t){
      *(f16x4*)(app + d00) = pend[0];
      *(f16x4*)(app + d01) = pend[1];
    }
    f16x4 xg[2][3];
#pragma unroll
    for (int q = 0; q < 2; ++q)
#pragma unroll
      for (int g = 0; g < 3; ++g)
        xg[q][g] = *(const f16x4*)(gp + g*256 + (2*wv+q)*16 + l4*4);

    const f16* rb = &a16[t & 1][l16][l4*8];

    f32x4 accr[2], accz[2];
#pragma unroll
    for (int q = 0; q < 2; ++q){ accr[q] = (f32x4){0.f,0.f,0.f,0.f};
                                 accz[q] = (f32x4){0.f,0.f,0.f,0.f}; }
#pragma unroll
    for (int kt = 0; kt < 8; ++kt){
      f16x8 bf = *(const f16x8*)(rb + kt*32);
#pragma unroll
      for (int q = 0; q < 2; ++q){
        accr[q] = __builtin_amdgcn_mfma_f32_16x16x32_f16(aW[q][0][kt], bf, accr[q], 0, 0, 0);
        accz[q] = __builtin_amdgcn_mfma_f32_16x16x32_f16(aW[q][1][kt], bf, accz[q], 0, 0, 0);
      }
    }
    f32x4 accn[2];
#pragma unroll
    for (int q = 0; q < 2; ++q) accn[q] = (f32x4){0.f,0.f,0.f,0.f};
#pragma unroll
    for (int kt = 0; kt < 8; ++kt){
      f16x8 bf = *(const f16x8*)(rb + kt*32);
#pragma unroll
      for (int q = 0; q < 2; ++q)
        accn[q] = __builtin_amdgcn_mfma_f32_16x16x32_f16(aW[q][2][kt], bf, accn[q], 0, 0, 0);
    }
    float rr[2][4], zz[2][4];
#pragma unroll
    for (int q = 0; q < 2; ++q)
#pragma unroll
      for (int r = 0; r < 4; ++r){
        rr[q][r] = fsig((float)xg[q][0][r] + accr[q][r]);
        zz[q][r] = fsig((float)xg[q][1][r] + accz[q][r]);
      }
    int nxt = (t & 1) ^ 1;
#pragma unroll
    for (int q = 0; q < 2; ++q){
      int d0 = (2*wv+q)*16 + l4*4;
      float4 bh4 = *(const float4*)(&bhnL[d0]);
      f16x4 hold = pend[q];
      f16x4 o4;
#pragma unroll
      for (int r = 0; r < 4; ++r){
        float bh = (r==0)?bh4.x:(r==1)?bh4.y:(r==2)?bh4.z:bh4.w;
        float nn = ftanh((float)xg[q][2][r] + rr[q][r]*(accn[q][r] + bh));
        float h2 = nn + zz[q][r]*((float)hold[r] - nn);
        o4[r] = (f16)h2;
      }
      *(f16x4*)(&a16[nxt][l16][d0]) = o4;
      pend[q] = o4;
    }
    app = ap; ap += astep;
    gp += 24576;
    __syncthreads();
  }
  *(f16x4*)(app + d00) = pend[0];
  *(f16x4*)(app + d01) = pend[1];
}

// ---------------------------------------------------------------------------
// K4: merged rnnout (blocks 0..63) + hidden (blocks 64..71).
__global__ __launch_bounds__(256) void k_post(const f16* __restrict__ Abuf,
                                              const f16* __restrict__ Ww16,
                                              const float* __restrict__ Wb,
                                              float* __restrict__ rnn,
                                              float* __restrict__ hidden,
                                              float* __restrict__ u){
  int bid = blockIdx.x;
  int lane = threadIdx.x & 63, wv = threadIdx.x >> 6;
  int l16 = lane & 15, l4 = lane >> 4;
  if (bid < 64){
    int mrow = bid*64 + wv*16;
    const f16* arow = Abuf + (size_t)(mrow + l16)*512;
    f16x8 af[16];
#pragma unroll
    for (int kt = 0; kt < 16; ++kt) af[kt] = *(const f16x8*)(arow + kt*32 + l4*8);
    for (int nt = 0; nt < 16; ++nt){
      int n = nt*16 + l16;
      const f16* brow = Ww16 + (size_t)n*512;
      f32x4 acc = {0.f,0.f,0.f,0.f};
#pragma unroll
      for (int kt = 0; kt < 16; ++kt){
        f16x8 bf = *(const f16x8*)(brow + kt*32 + l4*8);
        acc = __builtin_amdgcn_mfma_f32_16x16x32_f16(af[kt], bf, acc, 0, 0, 0);
      }
      float bias = Wb[n];
#pragma unroll
      for (int r = 0; r < 4; ++r)
        rnn[(size_t)(mrow + l4*4 + r)*256 + n] = acc[r] + bias;
    }
    return;
  }
  // hidden/u
  int hb = bid - 64;
  int mt = wv & 1, nt = hb*2 + (wv >> 1);
  int b = mt*16 + l16;
  const f16* rowf = Abuf + ((size_t)b*128 + 127)*512;
  const f16* rowb = Abuf + ((size_t)b*128)*512;
  f16x8 af[16];
#pragma unroll
  for (int kt = 0; kt < 16; ++kt){
    int k = kt*32 + l4*8;
    af[kt] = *(const f16x8*)((k < 256 ? rowf : rowb) + k);
  }
  int n = nt*16 + l16;
  const f16* brow = Ww16 + (size_t)n*512;
  f32x4 acc = {0.f,0.f,0.f,0.f};
#pragma unroll
  for (int kt = 0; kt < 16; ++kt){
    f16x8 bf = *(const f16x8*)(brow + kt*32 + l4*8);
    acc = __builtin_amdgcn_mfma_f32_16x16x32_f16(af[kt], bf, acc, 0, 0, 0);
  }
  float bias = Wb[n];
#pragma unroll
  for (int r = 0; r < 4; ++r){
    int bo = mt*16 + l4*4 + r;
    float v = acc[r] + bias;
    hidden[(size_t)bo*256 + n] = v;
    u[(size_t)bo*256 + n] = v;
  }
}

// ---------------------------------------------------------------------------
// K6a: logits[b][l] = (bag_raw[b][l] + lm_add) . u[b].
// bag may be a precomputed raw table-sum (f16, from mega-gather or bagbuf);
// if null, gather from tblA. rnn/lm-add ALWAYS applied inline here.
__global__ __launch_bounds__(256) void k_logits(const int* __restrict__ src,
                                                const int* __restrict__ kbl,
                                                const int* __restrict__ cvl,
                                                const float* __restrict__ tblA,
                                                const float* __restrict__ rnn,
                                                const float* __restrict__ u,
                                                float* __restrict__ logits,
                                                const f16* __restrict__ bag){
  int b = blockIdx.x >> 5, chunk = blockIdx.x & 31;
  int lane = threadIdx.x & 63, wv = threadIdx.x >> 6;
  int kb = kbl[b], cl = cvl[b];
  float4 uv = *(const float4*)(u + b*256 + lane*4);
#pragma unroll
  for (int i = 0; i < 4; ++i){
    int l = chunk*16 + wv*4 + i;
    float b0, b1, b2, b3;
    if (bag){
      f16x4 bv = *(const f16x4*)(bag + ((size_t)b*512 + l)*256 + lane*4);
      b0 = (float)bv[0]; b1 = (float)bv[1]; b2 = (float)bv[2]; b3 = (float)bv[3];
    } else {
      const int* sp = src + ((size_t)b*512 + l)*4;
      b0 = b1 = b2 = b3 = 0.f;
#pragma unroll
      for (int m = 0; m < 4; ++m){
        float4 wq = *(const float4*)(tblA + (size_t)sp[m]*256 + lane*4);
        b0 += wq.x; b1 += wq.y; b2 += wq.z; b3 += wq.w;
      }
    }
    int rel = l - kb;
    if (rel >= 0 && rel < cl){
      int rc = rel < 127 ? rel : 127;
      float4 rv = *(const float4*)(rnn + ((size_t)b*128 + rc)*256 + lane*4);
      b0 += rv.x; b1 += rv.y; b2 += rv.z; b3 += rv.w;
    }
    float p = b0*uv.x + b1*uv.y + b2*uv.z + b3*uv.w;
#pragma unroll
    for (int off = 32; off >= 1; off >>= 1) p += __shfl_down(p, off);
    if (lane == 0) logits[(size_t)b*512 + l] = p;
  }
}

// ---------------------------------------------------------------------------
// K6b: fused softmax + o_k. 512 blocks = (b<<4)|chunk, 32 l each.
// bagin: precomputed raw table-sum (mega-gather); else gather from tblC and
// (if bagout) store the RAW sum to bagbuf for the next hop's k_logits.
// rnn/lm-add applied inline (raw-bag semantics everywhere).
__global__ __launch_bounds__(256) void k_okv(const int* __restrict__ src,
                                             const int* __restrict__ kbl,
                                             const int* __restrict__ cvl,
                                             const float* __restrict__ tblC,
                                             const float* __restrict__ rnn,
                                             const float* __restrict__ logits,
                                             float* __restrict__ u,
                                             float* __restrict__ gp_out, int write_gp,
                                             const f16* __restrict__ bagin,
                                             f16* __restrict__ bagout){
  int b = blockIdx.x >> 4, c = blockIdx.x & 15;
  int d = threadIdx.x, lane = d & 63, wv = d >> 6;
  __shared__ float red[4];
  __shared__ float bc;
  __shared__ float pr[512];
  __shared__ int   sidx[128];

  float v0 = logits[(size_t)b*512 + d];
  float v1 = logits[(size_t)b*512 + 256 + d];
  float m = fmaxf(v0, v1);
#pragma unroll
  for (int off = 32; off >= 1; off >>= 1) m = fmaxf(m, __shfl_down(m, off));
  if (lane == 0) red[wv] = m;
  __syncthreads();
  if (d == 0) bc = fmaxf(fmaxf(red[0], red[1]), fmaxf(red[2], red[3]));
  __syncthreads();
  float mx = bc;
  float e0 = __expf(v0 - mx), e1 = __expf(v1 - mx);
  float s = e0 + e1;
#pragma unroll
  for (int off = 32; off >= 1; off >>= 1) s += __shfl_down(s, off);
  __syncthreads();
  if (lane == 0) red[wv] = s;
  __syncthreads();
  if (d == 0) bc = red[0] + red[1] + red[2] + red[3];
  __syncthreads();
  float inv = 1.0f/bc;
  pr[d] = e0*inv; pr[256 + d] = e1*inv;
  if (d < 128) sidx[d] = src[(size_t)b*2048 + c*128 + d];
  if (write_gp && c == 0){
    gp_out[(size_t)b*512 + d]       = fsig(v0);
    gp_out[(size_t)b*512 + 256 + d] = fsig(v1);
  }
  __syncthreads();

  int kb = kbl[b], cl = cvl[b];
  float acc = 0.f;
  for (int l = 0; l < 32; ++l){
    float bag;
    if (bagin){
      bag = (float)bagin[((size_t)b*512 + c*32 + l)*256 + d];
    } else {
      const int* sp = sidx + l*4;
      bag = tblC[(size_t)sp[0]*256 + d] + tblC[(size_t)sp[1]*256 + d]
          + tblC[(size_t)sp[2]*256 + d] + tblC[(size_t)sp[3]*256 + d];
      if (bagout) bagout[((size_t)b*512 + c*32 + l)*256 + d] = (f16)bag;  // RAW
    }
    int rel = (c*32 + l) - kb;
    if (rel >= 0 && rel < cl){
      int rc = rel < 127 ? rel : 127;
      bag += rnn[((size_t)b*128 + rc)*256 + d];
    }
    acc += pr[c*32 + l] * bag;
  }
  atomicAdd(&u[(size_t)b*256 + d], acc);
}

// ---------------------------------------------------------------------------
// K7: encoded[b][d] = relu(concat(hidden,u) . proj_w[d] + proj_b[d])  (fp32)
__global__ void k_encoded(const float* __restrict__ hidden, const float* __restrict__ u,
                          const float* __restrict__ pw, const float* __restrict__ pb,
                          float* __restrict__ out){
  int b = blockIdx.x, d = threadIdx.x;
  const float* w = pw + (size_t)d*512;
  float s = pb[d];
  for (int k = 0; k < 256; ++k) s += hidden[b*256 + k] * w[k];
  for (int k = 0; k < 256; ++k) s += u[b*256 + k]      * w[256 + k];
  out[(size_t)b*256 + d] = fmaxf(s, 0.f);
}

// ---------------------------------------------------------------------------
extern "C" void kernel_launch(void* const* d_in, const int* in_sizes, int n_in,
                              void* d_out, int out_size, void* d_ws, size_t ws_size,
                              hipStream_t stream){
  (void)in_sizes; (void)n_in; (void)out_size;
  float* out = (float*)d_out;  // [0:16384) global_pointer, [16384:24576) encoded

  const size_t WS_NEEDED = 25034752;
  if (ws_size < WS_NEEDED){
    k_zero<<<96, 256, 0, stream>>>(out);
    return;
  }

  const int* conv  = (const int*)d_in[0];
  const int* src   = (const int*)d_in[1];
  const int* kbl   = (const int*)d_in[2];
  const int* cvl   = (const int*)d_in[3];
  const float* emb_ctx = (const float*)d_in[4];
  const float* Ct      = (const float*)d_in[5];
  const float* Wih_f = (const float*)d_in[6];
  const float* Whh_f = (const float*)d_in[7];
  const float* bih_f = (const float*)d_in[8];
  const float* bhh_f = (const float*)d_in[9];
  const float* Wih_b = (const float*)d_in[10];
  const float* Whh_b = (const float*)d_in[11];
  const float* bih_b = (const float*)d_in[12];
  const float* bhh_b = (const float*)d_in[13];
  const float* Ww = (const float*)d_in[14];
  const float* Wb = (const float*)d_in[15];
  const float* pw = (const float*)d_in[16];
  const float* pb = (const float*)d_in[17];

  char* ws = (char*)d_ws;
  f16*   emb    = (f16*)(ws);                  //  2,097,152  [4096][256] f16
  f16*   gx_f   = (f16*)(ws + 2097152);        //  6,291,456  [t*32+b][768] f16
  f16*   gx_b   = (f16*)(ws + 8388608);        //  6,291,456
  f16*   Abuf   = (f16*)(ws + 14680064);       //  4,194,304  [b*128+t][512] f16
  float* rnn    = (float*)(ws + 18874368);     //  4,194,304  [b*128+t][256] f32
  float* hidden = (float*)(ws + 23068672);     //     32,768
  float* u      = (float*)(ws + 23101440);     //     32,768
  float* logits = (float*)(ws + 23134208);     //     65,536
  f16*   wihf16 = (f16*)(ws + 23199744);       //    393,216  [768][256]
  f16*   wihb16 = (f16*)(ws + 23592960);       //    393,216
  f16*   whhf16 = (f16*)(ws + 23986176);       //    393,216
  f16*   whhb16 = (f16*)(ws + 24379392);       //    393,216
  f16*   ww16   = (f16*)(ws + 24772608);       //    262,144  [256][512]
                                               // end 25,034,752
  // bagbuf (8.4 MB raw bag fallback) reuses gx region (dead after gru).
  f16*   bagbuf = (f16*)(ws + 2097152);
  // bagT slots beyond the base layout; priority T1, T2, T3, T0.
  f16*   bagT   = (f16*)(ws + WS_NEEDED);
  size_t avail  = ws_size - WS_NEEDED;
  int ntab = (int)(avail / 8388608); if (ntab > 4) ntab = 4;
  const int tabids[4] = {1, 2, 3, 0};
  const f16* bt[4] = {nullptr, nullptr, nullptr, nullptr};
  for (int s = 0; s < ntab; ++s) bt[tabids[s]] = bagT + (size_t)s*4194304;

  k_prep<<<4864, 256, 0, stream>>>(Wih_f, Wih_b, Whh_f, Whh_b, Ww,
                                   wihf16, wihb16, whhf16, whhb16, ww16,
                                   conv, emb_ctx, emb);
  k_gx2<<<128, 256, 0, stream>>>(emb, wihf16, wihb16,
                                 bih_f, bhh_f, bih_b, bhh_b, gx_f, gx_b);
  k_grumega<<<4 + 64*ntab, 512, 0, stream>>>(gx_f, gx_b, whhf16, whhb16,
                                             bhh_f, bhh_b, Abuf,
                                             src, Ct, bagT,
                                             tabids[0], tabids[1], tabids[2], tabids[3]);
  k_post<<<72, 256, 0, stream>>>(Abuf, ww16, Wb, rnn, hidden, u);

  for (int hop = 0; hop < 3; ++hop){
    const float* tA = Ct + (size_t)hop     * 32000 * 256;
    const float* tC = Ct + (size_t)(hop+1) * 32000 * 256;
    const f16* lbag = bt[hop] ? bt[hop] : (hop ? bagbuf : (const f16*)nullptr);
    const f16* obag = bt[hop + 1];
    f16* obout = (!obag && hop < 2) ? bagbuf : (f16*)nullptr;
    k_logits<<<1024, 256, 0, stream>>>(src, kbl, cvl, tA, rnn, u, logits, lbag);
    k_okv<<<512, 256, 0, stream>>>(src, kbl, cvl, tC, rnn, logits, u,
                                   out, hop == 2 ? 1 : 0, obag, obout);
  }
  k_encoded<<<32, 256, 0, stream>>>(hidden, u, pw, pb, out + 16384);
}